// Round 10
// baseline (687.584 us; speedup 1.0000x reference)
//
#include <hip/hip_runtime.h>
#include <math.h>

#define N_NODES 100000
#define N_EDGES 3200000
#define NEG 0.2f
#define NPB 128            // nodes per bucket
#define NB  782            // ceil(N_NODES / NPB)
#define CAP 4608           // staging capacity per bucket (mean 4096 + 8 sigma)
#define LOG2E 1.442695041f

typedef __attribute__((ext_vector_type(8))) short short8;
typedef __attribute__((ext_vector_type(4))) float f32x4;
typedef __attribute__((ext_vector_type(2))) float f32x2;

__device__ __forceinline__ float bflo(unsigned int u){
  union { unsigned int i; float f; } v; v.i = u << 16; return v.f;
}
__device__ __forceinline__ float bfhi(unsigned int u){
  union { unsigned int i; float f; } v; v.i = u & 0xffff0000u; return v.f;
}
__device__ __forceinline__ unsigned short f2bf(float f){
  union { float f; unsigned int i; } v; v.f = f;
  unsigned int r = v.i + 0x7fffu + ((v.i >> 16) & 1u);
  return (unsigned short)(r >> 16);
}
__device__ __forceinline__ unsigned int packbf(float lo, float hi){
  return (unsigned int)f2bf(lo) | ((unsigned int)f2bf(hi) << 16);
}
// packed dual-f32 FMA: acc.lo += a.lo*w.lo ; acc.hi += a.hi*w.hi
__device__ __forceinline__ void pk_fma(f32x2 &acc, f32x2 a, f32x2 w){
  asm("v_pk_fma_f32 %0, %1, %2, %0" : "+v"(acc) : "v"(a), "v"(w));
}
// weight: exp2(leaky_relu(t)) with t pre-scaled by log2e; fmax form is exact
__device__ __forceinline__ float wexp(float t){
  return __builtin_amdgcn_exp2f(fmaxf(t, NEG * t));
}
__device__ __forceinline__ f32x4 wexp4(f32x4 t){
  f32x4 r; r[0]=wexp(t[0]); r[1]=wexp(t[1]); r[2]=wexp(t[2]); r[3]=wexp(t[3]);
  return r;
}
// 8 bf16 dims of one edge's x-row, weighted into 4 per-head accumulators
__device__ __forceinline__ void fma_x8(f32x2 (*acc)[4], uint4 q, f32x4 w){
  f32x2 p0,p1,p2,p3;
  p0[0]=bflo(q.x); p0[1]=bfhi(q.x);
  p1[0]=bflo(q.y); p1[1]=bfhi(q.y);
  p2[0]=bflo(q.z); p2[1]=bfhi(q.z);
  p3[0]=bflo(q.w); p3[1]=bfhi(q.w);
  #pragma unroll
  for (int h=0;h<4;++h){
    f32x2 W; W[0]=w[h]; W[1]=w[h];
    pk_fma(acc[h][0], p0, W);
    pk_fma(acc[h][1], p1, W);
    pk_fma(acc[h][2], p2, W);
    pk_fma(acc[h][3], p3, W);
  }
}

// ---- prep: W1t, W2t, bucket cursors, score vectors val=W1*al / var=W1*ar ----
__global__ void k_prep(const float* __restrict__ W1, const float* __restrict__ W2,
                       const float* __restrict__ al1, const float* __restrict__ ar1,
                       unsigned short* __restrict__ W1t, unsigned short* __restrict__ W2t,
                       int* __restrict__ bcur, float* __restrict__ val,
                       float* __restrict__ var){
  int i = blockIdx.x*256 + threadIdx.x;
  if (i < 65536){ int n = i >> 7, k = i & 127; W1t[i] = f2bf(W1[k*512 + n]); }
  else if (i < 98304){ int j = i - 65536; int n = j >> 9, k = j & 511; W2t[j] = f2bf(W2[k*64 + n]); }
  else if (i < 98304 + NB){ int b = i - 98304; bcur[b*16] = b*CAP; }
  else if (i >= 99328 && i < 99840){
    int j = i - 99328; int k = j >> 2, h = j & 3;
    float s = 0.f;
    for (int d=0; d<128; ++d) s += W1[k*512 + h*128 + d] * al1[h*128 + d];
    val[j] = s;
  } else if (i >= 99840 && i < 100352){
    int j = i - 99840; int k = j >> 2, h = j & 3;
    float s = 0.f;
    for (int d=0; d<128; ++d) s += W1[k*512 + h*128 + d] * ar1[h*128 + d];
    var[j] = s;
  }
}

// ---- xcvt: x -> bf16 xb, plus layer-1 scores el/er = x . (val|var) ----
// quarter-wave per node: 16 lanes x 8 dims.
__global__ __launch_bounds__(256) void k_xcvt(const float* __restrict__ x,
    const float* __restrict__ val, const float* __restrict__ var,
    unsigned short* __restrict__ xb, float* __restrict__ el, float* __restrict__ er){
  int wave = threadIdx.x >> 6, lane = threadIdx.x & 63;
  int q = lane >> 4, ql = lane & 15;
  int n = (blockIdx.x*4 + wave)*4 + q;           // grid exact: 6250*16 = 100000
  f32x4 valr[8], varr[8];
  #pragma unroll
  for (int j=0;j<8;++j){
    valr[j] = *(const f32x4*)(val + (ql*8+j)*4);
    varr[j] = *(const f32x4*)(var + (ql*8+j)*4);
  }
  const float* xp = x + (size_t)n*128 + ql*8;
  float4 xa = *(const float4*)xp;
  float4 xc = *(const float4*)(xp + 4);
  uint4 o; o.x = packbf(xa.x,xa.y); o.y = packbf(xa.z,xa.w);
  o.z = packbf(xc.x,xc.y); o.w = packbf(xc.z,xc.w);
  *(uint4*)(xb + (size_t)n*128 + ql*8) = o;
  float xs[8] = {xa.x,xa.y,xa.z,xa.w,xc.x,xc.y,xc.z,xc.w};
  f32x4 e4; e4[0]=0.f; e4[1]=0.f; e4[2]=0.f; e4[3]=0.f;
  f32x4 r4 = e4;
  #pragma unroll
  for (int j=0;j<8;++j){
    e4 += valr[j] * xs[j];
    r4 += varr[j] * xs[j];
  }
  #pragma unroll
  for (int m=1;m<16;m<<=1){
    #pragma unroll
    for (int c=0;c<4;++c){
      e4[c] += __shfl_xor(e4[c], m);
      r4[c] += __shfl_xor(r4[c], m);
    }
  }
  if (ql == 0){
    f32x4 es = e4 * LOG2E, rs = r4 * LOG2E;   // pre-scale for exp2 weights
    *(f32x4*)(el + n*4) = es;
    *(f32x4*)(er + n*4) = rs;
  }
}

// ---- bucketed CSR build (fixed-capacity staging; no count pass) ----
__global__ void k_bucket(const int* __restrict__ src, const int* __restrict__ dst,
                         int* __restrict__ bcur, int* __restrict__ staged){
  int e = blockIdx.x*blockDim.x + threadIdx.x;
  if (e < N_EDGES){
    int d = dst[e];
    int b = d >> 7;
    int pos = atomicAdd(&bcur[b*16], 1);
    staged[pos] = (src[e] << 7) | (d & (NPB-1));
  }
}
// per-bucket counting sort; computes own global prefix (no bscan pass)
__global__ __launch_bounds__(256) void k_binsort(const int* __restrict__ staged,
    const int* __restrict__ bcur, int* __restrict__ csr_src,
    int* __restrict__ indptr){
  __shared__ int hist[NPB];
  __shared__ int scan[NPB];
  __shared__ int lcur[NPB];
  __shared__ int red[256];
  const int b = blockIdx.x, t = threadIdx.x;
  const int st0 = b*CAP;
  const int cnt = bcur[b*16] - st0;
  // obase = sum of counts of buckets < b (block reduction over strided slices)
  int part = 0;
  for (int i = t; i < b; i += 256) part += bcur[i*16] - i*CAP;
  red[t] = part;
  if (t < NPB) hist[t] = 0;
  __syncthreads();
  for (int off = 128; off > 0; off >>= 1){
    if (t < off) red[t] += red[t + off];
    __syncthreads();
  }
  const int obase = red[0];
  for (int i = t; i < cnt; i += 256)
    atomicAdd(&hist[staged[st0 + i] & (NPB-1)], 1);
  __syncthreads();
  int v = (t < NPB) ? hist[t] : 0;
  if (t < NPB) scan[t] = v;
  __syncthreads();
  for (int off=1; off<NPB; off<<=1){
    int u = (t < NPB && t >= off) ? scan[t-off] : 0;
    __syncthreads();
    if (t < NPB) scan[t] += u;
    __syncthreads();
  }
  const int node0 = b * NPB;
  if (t < NPB){
    int ex = obase + scan[t] - v;    // global exclusive offset for node0+t
    lcur[t] = ex;
    if (node0 + t < N_NODES) indptr[node0 + t] = ex;
  }
  if (b == NB-1 && t == 0) indptr[N_NODES] = N_EDGES;
  __syncthreads();
  for (int i = t; i < cnt; i += 256){
    int pv = staged[st0 + i];
    int pos = atomicAdd(&lcur[pv & (NPB-1)], 1);
    csr_src[pos] = pv >> 7;
  }
}

// ---- layer-1 aggregate over INPUT x (linearity: GEMM deferred to mmpost) ----
// quarter-wave per edge (16 lanes x 16B = 256B bf16 row); 16 edges in flight.
// 32-bit byte addressing throughout (tables < 4GB).
__global__ __launch_bounds__(256) void k_agg1(const unsigned short* __restrict__ xb,
    const float* __restrict__ el, const float* __restrict__ er,
    const int* __restrict__ indptr, const int* __restrict__ csr_src,
    unsigned short* __restrict__ sagg, float* __restrict__ ssumA){
  int wave = threadIdx.x >> 6, lane = threadIdx.x & 63;
  int n = blockIdx.x*4 + wave;
  if (n >= N_NODES) return;
  int p0 = indptr[n], p1 = indptr[n+1];
  const int q = lane >> 4, ql = lane & 15;
  const unsigned d0 = ql * 16u;                    // byte offset in 256B row
  const char* xbb = (const char*)xb;
  const char* elb = (const char*)el;
  f32x4 er4 = *(const f32x4*)(er + n*4);
  f32x4 ss; ss[0]=0.f; ss[1]=0.f; ss[2]=0.f; ss[3]=0.f;
  f32x2 acc[4][4];
  #pragma unroll
  for (int h=0;h<4;++h)
    #pragma unroll
    for (int j=0;j<4;++j){ acc[h][j][0]=0.f; acc[h][j][1]=0.f; }
  int e = p0;
  for (; e + 15 < p1; e += 16){
    unsigned s0 = (unsigned)csr_src[e + 0  + q];
    unsigned s1 = (unsigned)csr_src[e + 4  + q];
    unsigned s2 = (unsigned)csr_src[e + 8  + q];
    unsigned s3 = (unsigned)csr_src[e + 12 + q];
    uint4 q0 = *(const uint4*)(xbb + (s0 << 8) + d0);
    uint4 q1 = *(const uint4*)(xbb + (s1 << 8) + d0);
    uint4 q2 = *(const uint4*)(xbb + (s2 << 8) + d0);
    uint4 q3 = *(const uint4*)(xbb + (s3 << 8) + d0);
    f32x4 e0 = *(const f32x4*)(elb + (s0 << 4));
    f32x4 e1 = *(const f32x4*)(elb + (s1 << 4));
    f32x4 e2 = *(const f32x4*)(elb + (s2 << 4));
    f32x4 e3 = *(const f32x4*)(elb + (s3 << 4));
    f32x4 w0 = wexp4(e0 + er4);
    f32x4 w1 = wexp4(e1 + er4);
    f32x4 w2 = wexp4(e2 + er4);
    f32x4 w3 = wexp4(e3 + er4);
    ss += (w0 + w1) + (w2 + w3);
    fma_x8(acc, q0, w0);
    fma_x8(acc, q1, w1);
    fma_x8(acc, q2, w2);
    fma_x8(acc, q3, w3);
  }
  for (; e < p1; e += 4){
    int idx = e + q;
    bool ok = idx < p1;
    unsigned s = (unsigned)csr_src[ok ? idx : e];
    uint4 qq = *(const uint4*)(xbb + (s << 8) + d0);
    f32x4 ee = *(const f32x4*)(elb + (s << 4));
    f32x4 w = wexp4(ee + er4);
    if (!ok){ w[0]=0.f; w[1]=0.f; w[2]=0.f; w[3]=0.f; }
    ss += w;
    fma_x8(acc, qq, w);
  }
  // combine the 4 quarters (disjoint edge subsets, same dim mapping)
  #pragma unroll
  for (int m=16;m<64;m<<=1){
    #pragma unroll
    for (int c=0;c<4;++c) ss[c] += __shfl_xor(ss[c], m);
    #pragma unroll
    for (int h=0;h<4;++h)
      #pragma unroll
      for (int j=0;j<4;++j){
        acc[h][j][0] += __shfl_xor(acc[h][j][0], m);
        acc[h][j][1] += __shfl_xor(acc[h][j][1], m);
      }
  }
  if (q == 0){
    unsigned short* op = sagg + (size_t)n*512 + ql*8;
    #pragma unroll
    for (int h=0;h<4;++h){
      uint4 o;
      o.x = packbf(acc[h][0][0], acc[h][0][1]);
      o.y = packbf(acc[h][1][0], acc[h][1][1]);
      o.z = packbf(acc[h][2][0], acc[h][2][1]);
      o.w = packbf(acc[h][3][0], acc[h][3][1]);
      *(uint4*)(op + h*128) = o;
    }
    if (ql == 0) *(f32x4*)(ssumA + n*4) = ss;
  }
}

// ---- mmpost: h1 = ELU((s_agg . W1)/ssum), IN-PLACE over s_agg ----
// block (mtile, head): reads exactly the 128x128 tile it overwrites.
__global__ __launch_bounds__(256) void k_mmpost(unsigned short* __restrict__ sagg,
    const unsigned short* __restrict__ Bt, const float* __restrict__ ssumA, int M){
  __shared__ unsigned short sm[18432];          // As 128x72 | Bs 128x72
  unsigned short* As = sm;
  unsigned short* Bs = sm + 9216;
  const int t = threadIdx.x;
  const int w = t >> 6, l = t & 63;
  const int quad = l >> 4, l16 = l & 15;
  const int m0 = blockIdx.x * 128;
  const int h = blockIdx.y;
  const int moff = (w & 1) * 64, noff = (w >> 1) * 64;
  f32x4 acc[4][4];
  #pragma unroll
  for (int i=0;i<4;++i)
    #pragma unroll
    for (int j=0;j<4;++j){ acc[i][j][0]=0.f; acc[i][j][1]=0.f; acc[i][j][2]=0.f; acc[i][j][3]=0.f; }
  for (int kb = 0; kb < 2; ++kb){
    const int K0 = kb * 64;
    #pragma unroll
    for (int i=0;i<4;++i){              // A: s_agg head-slice, 128x64 bf16
      int idx = t + i*256;
      int row = idx >> 3, c8 = (idx & 7) * 8;
      uint4 v; v.x=0u; v.y=0u; v.z=0u; v.w=0u;
      if (m0 + row < M)
        v = *(const uint4*)(sagg + (size_t)(m0+row)*512 + h*128 + K0 + c8);
      *(uint4*)(As + row*72 + c8) = v;
    }
    #pragma unroll
    for (int i=0;i<4;++i){              // B: W1t rows h*128..+128
      int idx = t + i*256;
      int row = idx >> 3, c8 = (idx & 7) * 8;
      *(uint4*)(Bs + row*72 + c8) =
        *(const uint4*)(Bt + (size_t)(h*128 + row)*128 + K0 + c8);
    }
    __syncthreads();
    #pragma unroll
    for (int ks = 0; ks < 2; ++ks){
      short8 af[4], bfr[4];
      #pragma unroll
      for (int mi=0; mi<4; ++mi)
        af[mi] = *(const short8*)(As + (moff + mi*16 + l16)*72 + ks*32 + quad*8);
      #pragma unroll
      for (int ni=0; ni<4; ++ni)
        bfr[ni] = *(const short8*)(Bs + (noff + ni*16 + l16)*72 + ks*32 + quad*8);
      #pragma unroll
      for (int mi=0; mi<4; ++mi)
        #pragma unroll
        for (int ni=0; ni<4; ++ni)
          acc[mi][ni] = __builtin_amdgcn_mfma_f32_16x16x32_bf16(af[mi], bfr[ni], acc[mi][ni], 0,0,0);
    }
    __syncthreads();
  }
  // epilogue: divide by ssum, ELU, bf16, coalesced in-place store
  float invr[4][4];
  #pragma unroll
  for (int mi=0; mi<4; ++mi)
    #pragma unroll
    for (int r=0;r<4;++r){
      int gr = m0 + moff + mi*16 + quad*4 + r;
      float s = (gr < M) ? ssumA[gr*4 + h] : 0.f;
      invr[mi][r] = s > 0.f ? 1.f/s : 0.f;
    }
  unsigned short* Cs = sm;                       // 128x136 bf16 (34.8 KB)
  #pragma unroll
  for (int mi=0; mi<4; ++mi)
    #pragma unroll
    for (int ni=0; ni<4; ++ni){
      int col = noff + ni*16 + l16;
      int rb  = moff + mi*16 + quad*4;
      #pragma unroll
      for (int r=0;r<4;++r){
        float v = acc[mi][ni][r] * invr[mi][r];
        v = v > 0.f ? v : __expf(v) - 1.f;       // fused ELU
        Cs[(rb+r)*136 + col] = f2bf(v);
      }
    }
  __syncthreads();
  #pragma unroll
  for (int i=0;i<8;++i){
    int e = t + i*256;
    int row = e >> 4, c8 = (e & 15) * 8;
    if (m0 + row < M)
      *(uint4*)(sagg + (size_t)(m0+row)*512 + h*128 + c8) =
        *(const uint4*)(Cs + row*136 + c8);
  }
}

// ---- GEMM2 (MFMA) + fused layer-2 scores ----
__global__ __launch_bounds__(256) void k_mm2(const unsigned short* __restrict__ A,
    const unsigned short* __restrict__ Bt,
    unsigned short* __restrict__ C, int M,
    const float* __restrict__ al, const float* __restrict__ ar,
    float* __restrict__ el, float* __restrict__ er){
  __shared__ unsigned short sm[13824];          // As 128x72 | Bs 64x72 (27.6 KB)
  unsigned short* As = sm;
  unsigned short* Bs = sm + 9216;
  const int t = threadIdx.x;
  const int w = t >> 6, l = t & 63;
  const int quad = l >> 4, l16 = l & 15;
  const int m0 = blockIdx.x * 128;
  const int moff = w * 32;
  f32x4 acc[2][4];
  #pragma unroll
  for (int i=0;i<2;++i)
    #pragma unroll
    for (int j=0;j<4;++j){ acc[i][j][0]=0.f; acc[i][j][1]=0.f; acc[i][j][2]=0.f; acc[i][j][3]=0.f; }
  for (int kb = 0; kb < 8; ++kb){
    const int K0 = kb * 64;
    #pragma unroll
    for (int i=0;i<4;++i){
      int idx = t + i*256;
      int row = idx >> 3, c8 = (idx & 7) * 8;
      uint4 v; v.x=0u; v.y=0u; v.z=0u; v.w=0u;
      if (m0 + row < M) v = *(const uint4*)(A + (size_t)(m0+row)*512 + K0 + c8);
      *(uint4*)(As + row*72 + c8) = v;
    }
    #pragma unroll
    for (int i=0;i<2;++i){
      int idx = t + i*256;
      int row = idx >> 3, c8 = (idx & 7) * 8;
      *(uint4*)(Bs + row*72 + c8) = *(const uint4*)(Bt + (size_t)row*512 + K0 + c8);
    }
    __syncthreads();
    #pragma unroll
    for (int ks = 0; ks < 2; ++ks){
      short8 af[2], bfr[4];
      #pragma unroll
      for (int mi=0; mi<2; ++mi)
        af[mi] = *(const short8*)(As + (moff + mi*16 + l16)*72 + ks*32 + quad*8);
      #pragma unroll
      for (int ni=0; ni<4; ++ni)
        bfr[ni] = *(const short8*)(Bs + (ni*16 + l16)*72 + ks*32 + quad*8);
      #pragma unroll
      for (int mi=0; mi<2; ++mi)
        #pragma unroll
        for (int ni=0; ni<4; ++ni)
          acc[mi][ni] = __builtin_amdgcn_mfma_f32_16x16x32_bf16(af[mi], bfr[ni], acc[mi][ni], 0,0,0);
    }
    __syncthreads();
  }
  unsigned short* Cs = sm;                       // 128x72 bf16
  #pragma unroll
  for (int mi=0; mi<2; ++mi)
    #pragma unroll
    for (int ni=0; ni<4; ++ni){
      int col = ni*16 + l16;
      int rb  = moff + mi*16 + quad*4;
      #pragma unroll
      for (int r=0;r<4;++r) Cs[(rb+r)*72 + col] = f2bf(acc[mi][ni][r]);
    }
  __syncthreads();
  #pragma unroll
  for (int i=0;i<4;++i){
    int e = t + i*256;
    int row = e >> 3, c8 = (e & 7) * 8;
    if (m0 + row < M)
      *(uint4*)(C + (size_t)(m0+row)*64 + c8) = *(const uint4*)(Cs + row*72 + c8);
  }
  // fused scores: thread pair covers one row (32 cols each)
  {
    int row = t >> 1, half = t & 1;
    const float* alp = al + half*32;
    const float* arp = ar + half*32;
    const unsigned short* cp = Cs + row*72 + half*32;
    float se = 0.f, sr = 0.f;
    #pragma unroll
    for (int i=0;i<4;++i){
      uint4 q = *(const uint4*)(cp + i*8);
      float4 a0 = *(const float4*)(alp + i*8), a1 = *(const float4*)(alp + i*8 + 4);
      float4 r0 = *(const float4*)(arp + i*8), r1 = *(const float4*)(arp + i*8 + 4);
      se += bflo(q.x)*a0.x + bfhi(q.x)*a0.y + bflo(q.y)*a0.z + bfhi(q.y)*a0.w
          + bflo(q.z)*a1.x + bfhi(q.z)*a1.y + bflo(q.w)*a1.z + bfhi(q.w)*a1.w;
      sr += bflo(q.x)*r0.x + bfhi(q.x)*r0.y + bflo(q.y)*r0.z + bfhi(q.y)*r0.w
          + bflo(q.z)*r1.x + bfhi(q.z)*r1.y + bflo(q.w)*r1.z + bfhi(q.w)*r1.w;
    }
    se += __shfl_xor(se, 1); sr += __shfl_xor(sr, 1);
    if (half == 0 && m0 + row < M){
      el[m0+row] = se * LOG2E;   // pre-scale for exp2 weights
      er[m0+row] = sr * LOG2E;
    }
  }
}

// ---- layer-2 aggregate: eighth-wave per edge, 4-edge unroll, 32-bit addr ----
__global__ __launch_bounds__(256) void k_agg2(const unsigned short* __restrict__ feat,
    const float* __restrict__ el, const float* __restrict__ er,
    const int* __restrict__ indptr, const int* __restrict__ csr_src,
    float* __restrict__ out){
  int wave = threadIdx.x >> 6, lane = threadIdx.x & 63;
  int n = blockIdx.x*4 + wave;
  if (n >= N_NODES) return;
  int p0 = indptr[n], p1 = indptr[n+1];
  float ern = er[n];
  int g = lane >> 3, ql = lane & 7;
  const unsigned d0 = ql * 16u;                  // byte offset in 128B row
  const char* fb  = (const char*)feat;
  const char* elb = (const char*)el;
  float s = 0.f;
  f32x2 acc[4];
  #pragma unroll
  for (int i=0;i<4;++i){ acc[i][0]=0.f; acc[i][1]=0.f; }
  int e = p0 + g;
  for (; e + 24 < p1; e += 32){
    unsigned sa = (unsigned)csr_src[e];
    unsigned sb = (unsigned)csr_src[e+8];
    unsigned sc = (unsigned)csr_src[e+16];
    unsigned sd = (unsigned)csr_src[e+24];
    uint4 va = *(const uint4*)(fb + (sa << 7) + d0);
    uint4 vb = *(const uint4*)(fb + (sb << 7) + d0);
    uint4 vc = *(const uint4*)(fb + (sc << 7) + d0);
    uint4 vd = *(const uint4*)(fb + (sd << 7) + d0);
    float wa = wexp(*(const float*)(elb + (sa << 2)) + ern);
    float wb = wexp(*(const float*)(elb + (sb << 2)) + ern);
    float wc = wexp(*(const float*)(elb + (sc << 2)) + ern);
    float wd = wexp(*(const float*)(elb + (sd << 2)) + ern);
    s += (wa + wb) + (wc + wd);
    f32x2 W, a;
    W[0]=wa; W[1]=wa;
    a[0]=bflo(va.x); a[1]=bfhi(va.x); pk_fma(acc[0], a, W);
    a[0]=bflo(va.y); a[1]=bfhi(va.y); pk_fma(acc[1], a, W);
    a[0]=bflo(va.z); a[1]=bfhi(va.z); pk_fma(acc[2], a, W);
    a[0]=bflo(va.w); a[1]=bfhi(va.w); pk_fma(acc[3], a, W);
    W[0]=wb; W[1]=wb;
    a[0]=bflo(vb.x); a[1]=bfhi(vb.x); pk_fma(acc[0], a, W);
    a[0]=bflo(vb.y); a[1]=bfhi(vb.y); pk_fma(acc[1], a, W);
    a[0]=bflo(vb.z); a[1]=bfhi(vb.z); pk_fma(acc[2], a, W);
    a[0]=bflo(vb.w); a[1]=bfhi(vb.w); pk_fma(acc[3], a, W);
    W[0]=wc; W[1]=wc;
    a[0]=bflo(vc.x); a[1]=bfhi(vc.x); pk_fma(acc[0], a, W);
    a[0]=bflo(vc.y); a[1]=bfhi(vc.y); pk_fma(acc[1], a, W);
    a[0]=bflo(vc.z); a[1]=bfhi(vc.z); pk_fma(acc[2], a, W);
    a[0]=bflo(vc.w); a[1]=bfhi(vc.w); pk_fma(acc[3], a, W);
    W[0]=wd; W[1]=wd;
    a[0]=bflo(vd.x); a[1]=bfhi(vd.x); pk_fma(acc[0], a, W);
    a[0]=bflo(vd.y); a[1]=bfhi(vd.y); pk_fma(acc[1], a, W);
    a[0]=bflo(vd.z); a[1]=bfhi(vd.z); pk_fma(acc[2], a, W);
    a[0]=bflo(vd.w); a[1]=bfhi(vd.w); pk_fma(acc[3], a, W);
  }
  for (; e < p1; e += 8){
    unsigned si = (unsigned)csr_src[e];
    float w = wexp(*(const float*)(elb + (si << 2)) + ern);
    uint4 v = *(const uint4*)(fb + (si << 7) + d0);
    s += w;
    f32x2 W, a; W[0]=w; W[1]=w;
    a[0]=bflo(v.x); a[1]=bfhi(v.x); pk_fma(acc[0], a, W);
    a[0]=bflo(v.y); a[1]=bfhi(v.y); pk_fma(acc[1], a, W);
    a[0]=bflo(v.z); a[1]=bfhi(v.z); pk_fma(acc[2], a, W);
    a[0]=bflo(v.w); a[1]=bfhi(v.w); pk_fma(acc[3], a, W);
  }
  #pragma unroll
  for (int m=8;m<64;m<<=1){
    s += __shfl_xor(s,m);
    #pragma unroll
    for (int i=0;i<4;++i){
      acc[i][0] += __shfl_xor(acc[i][0],m);
      acc[i][1] += __shfl_xor(acc[i][1],m);
    }
  }
  float inv = s > 0.f ? 1.f/s : 0.f;
  if (g == 0){
    float* op = out + (size_t)n*64 + ql*8;
    *(float4*)op     = make_float4(acc[0][0]*inv, acc[0][1]*inv, acc[1][0]*inv, acc[1][1]*inv);
    *(float4*)(op+4) = make_float4(acc[2][0]*inv, acc[2][1]*inv, acc[3][0]*inv, acc[3][1]*inv);
  }
}

extern "C" void kernel_launch(void* const* d_in, const int* in_sizes, int n_in,
                              void* d_out, int out_size, void* d_ws, size_t ws_size,
                              hipStream_t stream){
  const float* x   = (const float*)d_in[0];
  const float* W1  = (const float*)d_in[1];
  const float* al1 = (const float*)d_in[2];
  const float* ar1 = (const float*)d_in[3];
  const float* W2  = (const float*)d_in[4];
  const float* al2 = (const float*)d_in[5];
  const float* ar2 = (const float*)d_in[6];
  const int* src   = (const int*)d_in[7];
  const int* dst   = (const int*)d_in[8];
  float* out = (float*)d_out;

  char* ws = (char*)d_ws;
  size_t off = 0;
  auto alloc = [&](size_t bytes)->char*{
    char* p = ws + off; off += (bytes + 255) & ~(size_t)255; return p;
  };
  unsigned short* xbuf = (unsigned short*)alloc((size_t)N_NODES*128*2);   // 25.6 MB bf16 x
  unsigned short* sagg = (unsigned short*)alloc((size_t)N_NODES*512*2);   // 102.4 MB; becomes h1 in-place
  float* ssumA = (float*)alloc((size_t)N_NODES*4*4);                      // 1.6 MB
  unsigned short* W1t = (unsigned short*)alloc(512*128*2);
  unsigned short* W2t = (unsigned short*)alloc(64*512*2);
  float* val  = (float*)alloc(512*4);
  float* var  = (float*)alloc(512*4);
  float* el1 = (float*)alloc((size_t)N_NODES*4*4);
  float* er1 = (float*)alloc((size_t)N_NODES*4*4);
  float* el2 = el1;                           // alias: el1 dead after k_agg1
  float* er2 = er1;
  int* bcur    = (int*)alloc((size_t)NB*16*4);        // padded: 1 counter / 64B
  int* indptr  = (int*)alloc((size_t)(N_NODES+1)*4);
  int* staged  = (int*)alloc((size_t)NB*CAP*4);                           // 14.4 MB
  int* csr_src = (int*)alloc((size_t)N_EDGES*4);                          // 12.8 MB
  unsigned short* feat2b = (unsigned short*)staged;  // alias: staged dead after binsort
  // total ~161 MB (< proven 222 MB footprint)

  dim3 b256(256);
  // prep: W1t, W2t, bucket cursors, score vectors (one launch)
  k_prep<<<dim3(392), b256, 0, stream>>>(W1, W2, al1, ar1, W1t, W2t, bcur, val, var);
  // x -> bf16 + layer-1 scores (GEMV via precomputed val/var)
  k_xcvt<<<dim3(6250), b256, 0, stream>>>(x, val, var, xbuf, el1, er1);
  // bucketed dst-CSR: scatter into fixed-capacity buckets -> per-bucket sort
  k_bucket<<<dim3((N_EDGES+255)/256), b256, 0, stream>>>(src, dst, bcur, staged);
  k_binsort<<<dim3(NB), b256, 0, stream>>>(staged, bcur, csr_src, indptr);
  // layer-1 aggregate over x (256B/edge gather; GEMM deferred)
  k_agg1<<<dim3(25000), b256, 0, stream>>>(xbuf, el1, er1, indptr, csr_src, sagg, ssumA);
  // deferred projection + softmax-div + ELU, in-place: sagg -> h1
  k_mmpost<<<dim3(782, 4), b256, 0, stream>>>(sagg, W1t, ssumA, N_NODES);
  // layer 2 (MFMA) + fused scores
  k_mm2<<<dim3(782), b256, 0, stream>>>(sagg, W2t, feat2b, N_NODES, al2, ar2, el2, er2);
  k_agg2<<<dim3(25000), b256, 0, stream>>>(feat2b, el2, er2, indptr, csr_src, out);
}

// Round 11
// 683.081 us; speedup vs baseline: 1.0066x; 1.0066x over previous
//
#include <hip/hip_runtime.h>
#include <math.h>

#define N_NODES 100000
#define N_EDGES 3200000
#define NEG 0.2f
#define NPB 128            // nodes per bucket
#define NB  782            // ceil(N_NODES / NPB)
#define CAP 4608           // staging capacity per bucket (mean 4096 + 8 sigma)
#define LOG2E 1.442695041f

typedef __attribute__((ext_vector_type(8))) short short8;
typedef __attribute__((ext_vector_type(4))) float f32x4;
typedef __attribute__((ext_vector_type(2))) float f32x2;

__device__ __forceinline__ float bflo(unsigned int u){
  union { unsigned int i; float f; } v; v.i = u << 16; return v.f;
}
__device__ __forceinline__ float bfhi(unsigned int u){
  union { unsigned int i; float f; } v; v.i = u & 0xffff0000u; return v.f;
}
__device__ __forceinline__ unsigned short f2bf(float f){
  union { float f; unsigned int i; } v; v.f = f;
  unsigned int r = v.i + 0x7fffu + ((v.i >> 16) & 1u);
  return (unsigned short)(r >> 16);
}
__device__ __forceinline__ unsigned int packbf(float lo, float hi){
  return (unsigned int)f2bf(lo) | ((unsigned int)f2bf(hi) << 16);
}
// packed dual-f32 FMA: acc.lo += a.lo*w.lo ; acc.hi += a.hi*w.hi
__device__ __forceinline__ void pk_fma(f32x2 &acc, f32x2 a, f32x2 w){
  asm("v_pk_fma_f32 %0, %1, %2, %0" : "+v"(acc) : "v"(a), "v"(w));
}
// weight: exp2(leaky_relu(t)) with t pre-scaled by log2e; fmax form is exact
__device__ __forceinline__ float wexp(float t){
  return __builtin_amdgcn_exp2f(fmaxf(t, NEG * t));
}
__device__ __forceinline__ f32x4 wexp4(f32x4 t){
  f32x4 r; r[0]=wexp(t[0]); r[1]=wexp(t[1]); r[2]=wexp(t[2]); r[3]=wexp(t[3]);
  return r;
}
// 8 bf16 dims of one edge's x-row, weighted into 4 per-head accumulators
__device__ __forceinline__ void fma_x8(f32x2 (*acc)[4], uint4 q, f32x4 w){
  f32x2 p0,p1,p2,p3;
  p0[0]=bflo(q.x); p0[1]=bfhi(q.x);
  p1[0]=bflo(q.y); p1[1]=bfhi(q.y);
  p2[0]=bflo(q.z); p2[1]=bfhi(q.z);
  p3[0]=bflo(q.w); p3[1]=bfhi(q.w);
  #pragma unroll
  for (int h=0;h<4;++h){
    f32x2 W; W[0]=w[h]; W[1]=w[h];
    pk_fma(acc[h][0], p0, W);
    pk_fma(acc[h][1], p1, W);
    pk_fma(acc[h][2], p2, W);
    pk_fma(acc[h][3], p3, W);
  }
}

// ---- prep: W1t, W2t, bucket cursors, score vectors val=W1*al / var=W1*ar ----
__global__ void k_prep(const float* __restrict__ W1, const float* __restrict__ W2,
                       const float* __restrict__ al1, const float* __restrict__ ar1,
                       unsigned short* __restrict__ W1t, unsigned short* __restrict__ W2t,
                       int* __restrict__ bcur, float* __restrict__ val,
                       float* __restrict__ var){
  int i = blockIdx.x*256 + threadIdx.x;
  if (i < 65536){ int n = i >> 7, k = i & 127; W1t[i] = f2bf(W1[k*512 + n]); }
  else if (i < 98304){ int j = i - 65536; int n = j >> 9, k = j & 511; W2t[j] = f2bf(W2[k*64 + n]); }
  else if (i < 98304 + NB){ int b = i - 98304; bcur[b*16] = b*CAP; }
  else if (i >= 99328 && i < 99840){
    int j = i - 99328; int k = j >> 2, h = j & 3;
    float s = 0.f;
    for (int d=0; d<128; ++d) s += W1[k*512 + h*128 + d] * al1[h*128 + d];
    val[j] = s;
  } else if (i >= 99840 && i < 100352){
    int j = i - 99840; int k = j >> 2, h = j & 3;
    float s = 0.f;
    for (int d=0; d<128; ++d) s += W1[k*512 + h*128 + d] * ar1[h*128 + d];
    var[j] = s;
  }
}

// ---- xcvt: x -> bf16 xb, plus layer-1 scores el/er = x . (val|var) ----
// quarter-wave per node: 16 lanes x 8 dims.
__global__ __launch_bounds__(256) void k_xcvt(const float* __restrict__ x,
    const float* __restrict__ val, const float* __restrict__ var,
    unsigned short* __restrict__ xb, float* __restrict__ el, float* __restrict__ er){
  int wave = threadIdx.x >> 6, lane = threadIdx.x & 63;
  int q = lane >> 4, ql = lane & 15;
  int n = (blockIdx.x*4 + wave)*4 + q;           // grid exact: 6250*16 = 100000
  f32x4 valr[8], varr[8];
  #pragma unroll
  for (int j=0;j<8;++j){
    valr[j] = *(const f32x4*)(val + (ql*8+j)*4);
    varr[j] = *(const f32x4*)(var + (ql*8+j)*4);
  }
  const float* xp = x + (size_t)n*128 + ql*8;
  float4 xa = *(const float4*)xp;
  float4 xc = *(const float4*)(xp + 4);
  uint4 o; o.x = packbf(xa.x,xa.y); o.y = packbf(xa.z,xa.w);
  o.z = packbf(xc.x,xc.y); o.w = packbf(xc.z,xc.w);
  *(uint4*)(xb + (size_t)n*128 + ql*8) = o;
  float xs[8] = {xa.x,xa.y,xa.z,xa.w,xc.x,xc.y,xc.z,xc.w};
  f32x4 e4; e4[0]=0.f; e4[1]=0.f; e4[2]=0.f; e4[3]=0.f;
  f32x4 r4 = e4;
  #pragma unroll
  for (int j=0;j<8;++j){
    e4 += valr[j] * xs[j];
    r4 += varr[j] * xs[j];
  }
  #pragma unroll
  for (int m=1;m<16;m<<=1){
    #pragma unroll
    for (int c=0;c<4;++c){
      e4[c] += __shfl_xor(e4[c], m);
      r4[c] += __shfl_xor(r4[c], m);
    }
  }
  if (ql == 0){
    f32x4 es = e4 * LOG2E, rs = r4 * LOG2E;   // pre-scale for exp2 weights
    *(f32x4*)(el + n*4) = es;
    *(f32x4*)(er + n*4) = rs;
  }
}

// ---- bucketed CSR build (fixed-capacity staging; no count pass) ----
__global__ void k_bucket(const int* __restrict__ src, const int* __restrict__ dst,
                         int* __restrict__ bcur, int* __restrict__ staged){
  int e = blockIdx.x*blockDim.x + threadIdx.x;
  if (e < N_EDGES){
    int d = dst[e];
    int b = d >> 7;
    int pos = atomicAdd(&bcur[b*16], 1);
    staged[pos] = (src[e] << 7) | (d & (NPB-1));
  }
}
// per-bucket counting sort; computes own global prefix (no bscan pass)
__global__ __launch_bounds__(256) void k_binsort(const int* __restrict__ staged,
    const int* __restrict__ bcur, int* __restrict__ csr_src,
    int* __restrict__ indptr){
  __shared__ int hist[NPB];
  __shared__ int scan[NPB];
  __shared__ int lcur[NPB];
  __shared__ int red[256];
  const int b = blockIdx.x, t = threadIdx.x;
  const int st0 = b*CAP;
  const int cnt = bcur[b*16] - st0;
  // obase = sum of counts of buckets < b (block reduction over strided slices)
  int part = 0;
  for (int i = t; i < b; i += 256) part += bcur[i*16] - i*CAP;
  red[t] = part;
  if (t < NPB) hist[t] = 0;
  __syncthreads();
  for (int off = 128; off > 0; off >>= 1){
    if (t < off) red[t] += red[t + off];
    __syncthreads();
  }
  const int obase = red[0];
  for (int i = t; i < cnt; i += 256)
    atomicAdd(&hist[staged[st0 + i] & (NPB-1)], 1);
  __syncthreads();
  int v = (t < NPB) ? hist[t] : 0;
  if (t < NPB) scan[t] = v;
  __syncthreads();
  for (int off=1; off<NPB; off<<=1){
    int u = (t < NPB && t >= off) ? scan[t-off] : 0;
    __syncthreads();
    if (t < NPB) scan[t] += u;
    __syncthreads();
  }
  const int node0 = b * NPB;
  if (t < NPB){
    int ex = obase + scan[t] - v;    // global exclusive offset for node0+t
    lcur[t] = ex;
    if (node0 + t < N_NODES) indptr[node0 + t] = ex;
  }
  if (b == NB-1 && t == 0) indptr[N_NODES] = N_EDGES;
  __syncthreads();
  for (int i = t; i < cnt; i += 256){
    int pv = staged[st0 + i];
    int pos = atomicAdd(&lcur[pv & (NPB-1)], 1);
    csr_src[pos] = pv >> 7;
  }
}

// ---- layer-1 aggregate over INPUT x (linearity: GEMM deferred to mmpost) ----
// quarter-wave per edge (16 lanes x 16B = 256B bf16 row); 16 edges in flight.
// 32-bit byte addressing throughout (tables < 4GB).
__global__ __launch_bounds__(256) void k_agg1(const unsigned short* __restrict__ xb,
    const float* __restrict__ el, const float* __restrict__ er,
    const int* __restrict__ indptr, const int* __restrict__ csr_src,
    unsigned short* __restrict__ sagg, float* __restrict__ ssumA){
  int wave = threadIdx.x >> 6, lane = threadIdx.x & 63;
  int n = blockIdx.x*4 + wave;
  if (n >= N_NODES) return;
  int p0 = indptr[n], p1 = indptr[n+1];
  const int q = lane >> 4, ql = lane & 15;
  const unsigned d0 = ql * 16u;                    // byte offset in 256B row
  const char* xbb = (const char*)xb;
  const char* elb = (const char*)el;
  f32x4 er4 = *(const f32x4*)(er + n*4);
  f32x4 ss; ss[0]=0.f; ss[1]=0.f; ss[2]=0.f; ss[3]=0.f;
  f32x2 acc[4][4];
  #pragma unroll
  for (int h=0;h<4;++h)
    #pragma unroll
    for (int j=0;j<4;++j){ acc[h][j][0]=0.f; acc[h][j][1]=0.f; }
  int e = p0;
  for (; e + 15 < p1; e += 16){
    unsigned s0 = (unsigned)csr_src[e + 0  + q];
    unsigned s1 = (unsigned)csr_src[e + 4  + q];
    unsigned s2 = (unsigned)csr_src[e + 8  + q];
    unsigned s3 = (unsigned)csr_src[e + 12 + q];
    uint4 q0 = *(const uint4*)(xbb + (s0 << 8) + d0);
    uint4 q1 = *(const uint4*)(xbb + (s1 << 8) + d0);
    uint4 q2 = *(const uint4*)(xbb + (s2 << 8) + d0);
    uint4 q3 = *(const uint4*)(xbb + (s3 << 8) + d0);
    f32x4 e0 = *(const f32x4*)(elb + (s0 << 4));
    f32x4 e1 = *(const f32x4*)(elb + (s1 << 4));
    f32x4 e2 = *(const f32x4*)(elb + (s2 << 4));
    f32x4 e3 = *(const f32x4*)(elb + (s3 << 4));
    f32x4 w0 = wexp4(e0 + er4);
    f32x4 w1 = wexp4(e1 + er4);
    f32x4 w2 = wexp4(e2 + er4);
    f32x4 w3 = wexp4(e3 + er4);
    ss += (w0 + w1) + (w2 + w3);
    fma_x8(acc, q0, w0);
    fma_x8(acc, q1, w1);
    fma_x8(acc, q2, w2);
    fma_x8(acc, q3, w3);
  }
  for (; e < p1; e += 4){
    int idx = e + q;
    bool ok = idx < p1;
    unsigned s = (unsigned)csr_src[ok ? idx : e];
    uint4 qq = *(const uint4*)(xbb + (s << 8) + d0);
    f32x4 ee = *(const f32x4*)(elb + (s << 4));
    f32x4 w = wexp4(ee + er4);
    if (!ok){ w[0]=0.f; w[1]=0.f; w[2]=0.f; w[3]=0.f; }
    ss += w;
    fma_x8(acc, qq, w);
  }
  // combine the 4 quarters (disjoint edge subsets, same dim mapping)
  #pragma unroll
  for (int m=16;m<64;m<<=1){
    #pragma unroll
    for (int c=0;c<4;++c) ss[c] += __shfl_xor(ss[c], m);
    #pragma unroll
    for (int h=0;h<4;++h)
      #pragma unroll
      for (int j=0;j<4;++j){
        acc[h][j][0] += __shfl_xor(acc[h][j][0], m);
        acc[h][j][1] += __shfl_xor(acc[h][j][1], m);
      }
  }
  if (q == 0){
    unsigned short* op = sagg + (size_t)n*512 + ql*8;
    #pragma unroll
    for (int h=0;h<4;++h){
      uint4 o;
      o.x = packbf(acc[h][0][0], acc[h][0][1]);
      o.y = packbf(acc[h][1][0], acc[h][1][1]);
      o.z = packbf(acc[h][2][0], acc[h][2][1]);
      o.w = packbf(acc[h][3][0], acc[h][3][1]);
      *(uint4*)(op + h*128) = o;
    }
    if (ql == 0) *(f32x4*)(ssumA + n*4) = ss;
  }
}

// ---- mmpost: h1 = ELU((s_agg . W1)/ssum), IN-PLACE over s_agg ----
// block (mtile, head): reads exactly the 128x128 tile it overwrites.
__global__ __launch_bounds__(256) void k_mmpost(unsigned short* __restrict__ sagg,
    const unsigned short* __restrict__ Bt, const float* __restrict__ ssumA, int M){
  __shared__ unsigned short sm[18432];          // As 128x72 | Bs 128x72
  unsigned short* As = sm;
  unsigned short* Bs = sm + 9216;
  const int t = threadIdx.x;
  const int w = t >> 6, l = t & 63;
  const int quad = l >> 4, l16 = l & 15;
  const int m0 = blockIdx.x * 128;
  const int h = blockIdx.y;
  const int moff = (w & 1) * 64, noff = (w >> 1) * 64;
  f32x4 acc[4][4];
  #pragma unroll
  for (int i=0;i<4;++i)
    #pragma unroll
    for (int j=0;j<4;++j){ acc[i][j][0]=0.f; acc[i][j][1]=0.f; acc[i][j][2]=0.f; acc[i][j][3]=0.f; }
  for (int kb = 0; kb < 2; ++kb){
    const int K0 = kb * 64;
    #pragma unroll
    for (int i=0;i<4;++i){              // A: s_agg head-slice, 128x64 bf16
      int idx = t + i*256;
      int row = idx >> 3, c8 = (idx & 7) * 8;
      uint4 v; v.x=0u; v.y=0u; v.z=0u; v.w=0u;
      if (m0 + row < M)
        v = *(const uint4*)(sagg + (size_t)(m0+row)*512 + h*128 + K0 + c8);
      *(uint4*)(As + row*72 + c8) = v;
    }
    #pragma unroll
    for (int i=0;i<4;++i){              // B: W1t rows h*128..+128
      int idx = t + i*256;
      int row = idx >> 3, c8 = (idx & 7) * 8;
      *(uint4*)(Bs + row*72 + c8) =
        *(const uint4*)(Bt + (size_t)(h*128 + row)*128 + K0 + c8);
    }
    __syncthreads();
    #pragma unroll
    for (int ks = 0; ks < 2; ++ks){
      short8 af[4], bfr[4];
      #pragma unroll
      for (int mi=0; mi<4; ++mi)
        af[mi] = *(const short8*)(As + (moff + mi*16 + l16)*72 + ks*32 + quad*8);
      #pragma unroll
      for (int ni=0; ni<4; ++ni)
        bfr[ni] = *(const short8*)(Bs + (noff + ni*16 + l16)*72 + ks*32 + quad*8);
      #pragma unroll
      for (int mi=0; mi<4; ++mi)
        #pragma unroll
        for (int ni=0; ni<4; ++ni)
          acc[mi][ni] = __builtin_amdgcn_mfma_f32_16x16x32_bf16(af[mi], bfr[ni], acc[mi][ni], 0,0,0);
    }
    __syncthreads();
  }
  // epilogue: divide by ssum, ELU, bf16, coalesced in-place store
  float invr[4][4];
  #pragma unroll
  for (int mi=0; mi<4; ++mi)
    #pragma unroll
    for (int r=0;r<4;++r){
      int gr = m0 + moff + mi*16 + quad*4 + r;
      float s = (gr < M) ? ssumA[gr*4 + h] : 0.f;
      invr[mi][r] = s > 0.f ? 1.f/s : 0.f;
    }
  unsigned short* Cs = sm;                       // 128x136 bf16 (34.8 KB)
  #pragma unroll
  for (int mi=0; mi<4; ++mi)
    #pragma unroll
    for (int ni=0; ni<4; ++ni){
      int col = noff + ni*16 + l16;
      int rb  = moff + mi*16 + quad*4;
      #pragma unroll
      for (int r=0;r<4;++r){
        float v = acc[mi][ni][r] * invr[mi][r];
        v = v > 0.f ? v : __expf(v) - 1.f;       // fused ELU
        Cs[(rb+r)*136 + col] = f2bf(v);
      }
    }
  __syncthreads();
  #pragma unroll
  for (int i=0;i<8;++i){
    int e = t + i*256;
    int row = e >> 4, c8 = (e & 15) * 8;
    if (m0 + row < M)
      *(uint4*)(sagg + (size_t)(m0+row)*512 + h*128 + c8) =
        *(const uint4*)(Cs + row*136 + c8);
  }
}

// ---- GEMM2 (MFMA) + fused layer-2 scores ----
__global__ __launch_bounds__(256) void k_mm2(const unsigned short* __restrict__ A,
    const unsigned short* __restrict__ Bt,
    unsigned short* __restrict__ C, int M,
    const float* __restrict__ al, const float* __restrict__ ar,
    float* __restrict__ el, float* __restrict__ er){
  __shared__ unsigned short sm[13824];          // As 128x72 | Bs 64x72 (27.6 KB)
  unsigned short* As = sm;
  unsigned short* Bs = sm + 9216;
  const int t = threadIdx.x;
  const int w = t >> 6, l = t & 63;
  const int quad = l >> 4, l16 = l & 15;
  const int m0 = blockIdx.x * 128;
  const int moff = w * 32;
  f32x4 acc[2][4];
  #pragma unroll
  for (int i=0;i<2;++i)
    #pragma unroll
    for (int j=0;j<4;++j){ acc[i][j][0]=0.f; acc[i][j][1]=0.f; acc[i][j][2]=0.f; acc[i][j][3]=0.f; }
  for (int kb = 0; kb < 8; ++kb){
    const int K0 = kb * 64;
    #pragma unroll
    for (int i=0;i<4;++i){
      int idx = t + i*256;
      int row = idx >> 3, c8 = (idx & 7) * 8;
      uint4 v; v.x=0u; v.y=0u; v.z=0u; v.w=0u;
      if (m0 + row < M) v = *(const uint4*)(A + (size_t)(m0+row)*512 + K0 + c8);
      *(uint4*)(As + row*72 + c8) = v;
    }
    #pragma unroll
    for (int i=0;i<2;++i){
      int idx = t + i*256;
      int row = idx >> 3, c8 = (idx & 7) * 8;
      *(uint4*)(Bs + row*72 + c8) = *(const uint4*)(Bt + (size_t)row*512 + K0 + c8);
    }
    __syncthreads();
    #pragma unroll
    for (int ks = 0; ks < 2; ++ks){
      short8 af[2], bfr[4];
      #pragma unroll
      for (int mi=0; mi<2; ++mi)
        af[mi] = *(const short8*)(As + (moff + mi*16 + l16)*72 + ks*32 + quad*8);
      #pragma unroll
      for (int ni=0; ni<4; ++ni)
        bfr[ni] = *(const short8*)(Bs + (ni*16 + l16)*72 + ks*32 + quad*8);
      #pragma unroll
      for (int mi=0; mi<2; ++mi)
        #pragma unroll
        for (int ni=0; ni<4; ++ni)
          acc[mi][ni] = __builtin_amdgcn_mfma_f32_16x16x32_bf16(af[mi], bfr[ni], acc[mi][ni], 0,0,0);
    }
    __syncthreads();
  }
  unsigned short* Cs = sm;                       // 128x72 bf16
  #pragma unroll
  for (int mi=0; mi<2; ++mi)
    #pragma unroll
    for (int ni=0; ni<4; ++ni){
      int col = ni*16 + l16;
      int rb  = moff + mi*16 + quad*4;
      #pragma unroll
      for (int r=0;r<4;++r) Cs[(rb+r)*72 + col] = f2bf(acc[mi][ni][r]);
    }
  __syncthreads();
  #pragma unroll
  for (int i=0;i<4;++i){
    int e = t + i*256;
    int row = e >> 3, c8 = (e & 7) * 8;
    if (m0 + row < M)
      *(uint4*)(C + (size_t)(m0+row)*64 + c8) = *(const uint4*)(Cs + row*72 + c8);
  }
  // fused scores: thread pair covers one row (32 cols each)
  {
    int row = t >> 1, half = t & 1;
    const float* alp = al + half*32;
    const float* arp = ar + half*32;
    const unsigned short* cp = Cs + row*72 + half*32;
    float se = 0.f, sr = 0.f;
    #pragma unroll
    for (int i=0;i<4;++i){
      uint4 q = *(const uint4*)(cp + i*8);
      float4 a0 = *(const float4*)(alp + i*8), a1 = *(const float4*)(alp + i*8 + 4);
      float4 r0 = *(const float4*)(arp + i*8), r1 = *(const float4*)(arp + i*8 + 4);
      se += bflo(q.x)*a0.x + bfhi(q.x)*a0.y + bflo(q.y)*a0.z + bfhi(q.y)*a0.w
          + bflo(q.z)*a1.x + bfhi(q.z)*a1.y + bflo(q.w)*a1.z + bfhi(q.w)*a1.w;
      sr += bflo(q.x)*r0.x + bfhi(q.x)*r0.y + bflo(q.y)*r0.z + bfhi(q.y)*r0.w
          + bflo(q.z)*r1.x + bfhi(q.z)*r1.y + bflo(q.w)*r1.z + bfhi(q.w)*r1.w;
    }
    se += __shfl_xor(se, 1); sr += __shfl_xor(sr, 1);
    if (half == 0 && m0 + row < M){
      el[m0+row] = se * LOG2E;   // pre-scale for exp2 weights
      er[m0+row] = sr * LOG2E;
    }
  }
}

// ---- layer-2 aggregate: eighth-wave per edge, 2-edge unroll, 32-bit addr ----
__global__ __launch_bounds__(256) void k_agg2(const unsigned short* __restrict__ feat,
    const float* __restrict__ el, const float* __restrict__ er,
    const int* __restrict__ indptr, const int* __restrict__ csr_src,
    float* __restrict__ out){
  int wave = threadIdx.x >> 6, lane = threadIdx.x & 63;
  int n = blockIdx.x*4 + wave;
  if (n >= N_NODES) return;
  int p0 = indptr[n], p1 = indptr[n+1];
  float ern = er[n];
  int g = lane >> 3, ql = lane & 7;
  const unsigned d0 = ql * 16u;                  // byte offset in 128B row
  const char* fb  = (const char*)feat;
  const char* elb = (const char*)el;
  float s = 0.f;
  f32x2 acc[4];
  #pragma unroll
  for (int i=0;i<4;++i){ acc[i][0]=0.f; acc[i][1]=0.f; }
  int e = p0 + g;
  for (; e + 8 < p1; e += 16){
    unsigned sa = (unsigned)csr_src[e];
    unsigned sb = (unsigned)csr_src[e+8];
    uint4 va = *(const uint4*)(fb + (sa << 7) + d0);
    uint4 vb = *(const uint4*)(fb + (sb << 7) + d0);
    float wa = wexp(*(const float*)(elb + (sa << 2)) + ern);
    float wb = wexp(*(const float*)(elb + (sb << 2)) + ern);
    s += wa + wb;
    f32x2 Wa; Wa[0]=wa; Wa[1]=wa;
    f32x2 Wb; Wb[0]=wb; Wb[1]=wb;
    f32x2 a;
    a[0]=bflo(va.x); a[1]=bfhi(va.x); pk_fma(acc[0], a, Wa);
    a[0]=bflo(va.y); a[1]=bfhi(va.y); pk_fma(acc[1], a, Wa);
    a[0]=bflo(va.z); a[1]=bfhi(va.z); pk_fma(acc[2], a, Wa);
    a[0]=bflo(va.w); a[1]=bfhi(va.w); pk_fma(acc[3], a, Wa);
    a[0]=bflo(vb.x); a[1]=bfhi(vb.x); pk_fma(acc[0], a, Wb);
    a[0]=bflo(vb.y); a[1]=bfhi(vb.y); pk_fma(acc[1], a, Wb);
    a[0]=bflo(vb.z); a[1]=bfhi(vb.z); pk_fma(acc[2], a, Wb);
    a[0]=bflo(vb.w); a[1]=bfhi(vb.w); pk_fma(acc[3], a, Wb);
  }
  for (; e < p1; e += 8){
    unsigned si = (unsigned)csr_src[e];
    float w = wexp(*(const float*)(elb + (si << 2)) + ern);
    uint4 v = *(const uint4*)(fb + (si << 7) + d0);
    s += w;
    f32x2 W, a; W[0]=w; W[1]=w;
    a[0]=bflo(v.x); a[1]=bfhi(v.x); pk_fma(acc[0], a, W);
    a[0]=bflo(v.y); a[1]=bfhi(v.y); pk_fma(acc[1], a, W);
    a[0]=bflo(v.z); a[1]=bfhi(v.z); pk_fma(acc[2], a, W);
    a[0]=bflo(v.w); a[1]=bfhi(v.w); pk_fma(acc[3], a, W);
  }
  #pragma unroll
  for (int m=8;m<64;m<<=1){
    s += __shfl_xor(s,m);
    #pragma unroll
    for (int i=0;i<4;++i){
      acc[i][0] += __shfl_xor(acc[i][0],m);
      acc[i][1] += __shfl_xor(acc[i][1],m);
    }
  }
  float inv = s > 0.f ? 1.f/s : 0.f;
  if (g == 0){
    float* op = out + (size_t)n*64 + ql*8;
    *(float4*)op     = make_float4(acc[0][0]*inv, acc[0][1]*inv, acc[1][0]*inv, acc[1][1]*inv);
    *(float4*)(op+4) = make_float4(acc[2][0]*inv, acc[2][1]*inv, acc[3][0]*inv, acc[3][1]*inv);
  }
}

extern "C" void kernel_launch(void* const* d_in, const int* in_sizes, int n_in,
                              void* d_out, int out_size, void* d_ws, size_t ws_size,
                              hipStream_t stream){
  const float* x   = (const float*)d_in[0];
  const float* W1  = (const float*)d_in[1];
  const float* al1 = (const float*)d_in[2];
  const float* ar1 = (const float*)d_in[3];
  const float* W2  = (const float*)d_in[4];
  const float* al2 = (const float*)d_in[5];
  const float* ar2 = (const float*)d_in[6];
  const int* src   = (const int*)d_in[7];
  const int* dst   = (const int*)d_in[8];
  float* out = (float*)d_out;

  char* ws = (char*)d_ws;
  size_t off = 0;
  auto alloc = [&](size_t bytes)->char*{
    char* p = ws + off; off += (bytes + 255) & ~(size_t)255; return p;
  };
  unsigned short* xbuf = (unsigned short*)alloc((size_t)N_NODES*128*2);   // 25.6 MB bf16 x
  unsigned short* sagg = (unsigned short*)alloc((size_t)N_NODES*512*2);   // 102.4 MB; becomes h1 in-place
  float* ssumA = (float*)alloc((size_t)N_NODES*4*4);                      // 1.6 MB
  unsigned short* W1t = (unsigned short*)alloc(512*128*2);
  unsigned short* W2t = (unsigned short*)alloc(64*512*2);
  float* val  = (float*)alloc(512*4);
  float* var  = (float*)alloc(512*4);
  float* el1 = (float*)alloc((size_t)N_NODES*4*4);
  float* er1 = (float*)alloc((size_t)N_NODES*4*4);
  float* el2 = el1;                           // alias: el1 dead after k_agg1
  float* er2 = er1;
  int* bcur    = (int*)alloc((size_t)NB*16*4);        // padded: 1 counter / 64B
  int* indptr  = (int*)alloc((size_t)(N_NODES+1)*4);
  int* staged  = (int*)alloc((size_t)NB*CAP*4);                           // 14.4 MB
  int* csr_src = (int*)alloc((size_t)N_EDGES*4);                          // 12.8 MB
  unsigned short* feat2b = (unsigned short*)staged;  // alias: staged dead after binsort
  // total ~161 MB (< proven 222 MB footprint)

  dim3 b256(256);
  // prep: W1t, W2t, bucket cursors, score vectors (one launch)
  k_prep<<<dim3(392), b256, 0, stream>>>(W1, W2, al1, ar1, W1t, W2t, bcur, val, var);
  // x -> bf16 + layer-1 scores (GEMV via precomputed val/var)
  k_xcvt<<<dim3(6250), b256, 0, stream>>>(x, val, var, xbuf, el1, er1);
  // bucketed dst-CSR: scatter into fixed-capacity buckets -> per-bucket sort
  k_bucket<<<dim3((N_EDGES+255)/256), b256, 0, stream>>>(src, dst, bcur, staged);
  k_binsort<<<dim3(NB), b256, 0, stream>>>(staged, bcur, csr_src, indptr);
  // layer-1 aggregate over x (256B/edge gather; GEMM deferred)
  k_agg1<<<dim3(25000), b256, 0, stream>>>(xbuf, el1, er1, indptr, csr_src, sagg, ssumA);
  // deferred projection + softmax-div + ELU, in-place: sagg -> h1
  k_mmpost<<<dim3(782, 4), b256, 0, stream>>>(sagg, W1t, ssumA, N_NODES);
  // layer 2 (MFMA) + fused scores
  k_mm2<<<dim3(782), b256, 0, stream>>>(sagg, W2t, feat2b, N_NODES, al2, ar2, el2, er2);
  k_agg2<<<dim3(25000), b256, 0, stream>>>(feat2b, el2, er2, indptr, csr_src, out);
}